// Round 4
// baseline (3120.020 us; speedup 1.0000x reference)
//
#include <hip/hip_runtime.h>
#include <math.h>

// ============================================================================
// VanillaEncoder — round 4: identical design to round 3 (bf16x3 split-precision
// MFMA for qkv/proj/fc1/fc2; f32-VALU tiled GEMM for attention + fusion).
// Changes this round: portable element-wise accumulator zero-init (removes the
// last known compile risk); no functional changes. Full alias/bank/guard audit
// re-done — see round notes.
//
// a*b ~= ah*bh + ah*bl + al*bh  (hi/lo bf16 split, fp32 MFMA accumulate)
//
// Workspace layout (bytes), alias-audited against strictly sequential order:
//   AHI  [0,        19365888)   A hi bf16 [12608][768]
//   ALO  [19365888, 38731776)   A lo
//   GHI  [40894464, 118358016)  gelu hi bf16 [12608][3072]
//   GLO  [118358016,195821568)  gelu lo
//   CONCAT/SCORES = 0           (fusion stage / per-stream scores; dead-time
//                                overlap with AHI/ALO/GHI/GLO-head verified)
//   QKV   = 125829120 (overlaps GLO; G-pair only live fc1->fc2, qkv dead then)
//   FUSED = 242221056  S1T = 248512512  A2 = 252706816  S2 = 256901120
//   P1    = 258998272 (38.7MB attn_out f32)
//   WHI   = 297795584  WLO = 303038464   (ends 307757056, ~294 MiB)
// ============================================================================

namespace {

constexpr int BB = 64, NN = 197, DD = 768, HH = 12, HDIM = 64, FF = 3072, LL = 32;
constexpr int N2 = 2 * NN;                 // 394
constexpr int ROWS = BB * NN;              // 12608
constexpr float SCALE_D = 0.036084391824351615f;  // 768^-0.5
constexpr float SCALE_H = 0.125f;                 // 64^-0.5

// ---- workspace byte offsets ----
constexpr long long B_AHI    = 0;
constexpr long long B_ALO    = 19365888;
constexpr long long B_GHI    = 40894464;
constexpr long long B_GLO    = 118358016;
constexpr long long B_CONCAT = 0;
constexpr long long B_SCORES = 0;
constexpr long long B_QKV    = 125829120;
constexpr long long B_FUSED  = 242221056;
constexpr long long B_S1T    = 248512512;
constexpr long long B_A2     = 252706816;
constexpr long long B_S2     = 256901120;
constexpr long long B_P1     = 258998272;
constexpr long long B_WHI    = 297795584;
constexpr long long B_WLO    = 303038464;

__device__ inline ushort f2bf(float f) {
  unsigned x = __float_as_uint(f);
  unsigned r = (x + 0x7FFFu + ((x >> 16) & 1u)) >> 16;
  return (ushort)r;
}
__device__ inline float bf2f(ushort u) {
  return __uint_as_float(((unsigned)u) << 16);
}

// ============================ MFMA bf16x3 GEMM =============================
using bf16x8v = __attribute__((ext_vector_type(8))) short;
using f32x4v  = __attribute__((ext_vector_type(4))) float;

enum { ME_BIAS = 0, ME_RESID_BIAS = 1, ME_GELU_SPLIT = 2 };

struct MP {
  const ushort* Ah; const ushort* Al; int lda;   // A pair, [M][lda] bf16
  const ushort* Wh; const ushort* Wl; int ldw;   // W pair, [N][ldw] bf16 (pre-transposed)
  float* C; int ldc;                              // f32 out (BIAS / RESID_BIAS)
  const float* bias;
  const float* R; int ldr;                        // residual (RESID_BIAS)
  ushort* Oh; ushort* Ol; int ldo;                // bf16 pair out (GELU_SPLIT)
  int M, N, K;
};

// BM=BN=128, BK=32, 256 threads (4 waves, 2x2), 64x64 per wave, 16x16x32 MFMA.
// LDS rows padded to 40 shorts (80B, 16B-aligned): fragment ds_read_b128 with
// per-lane row=fr hits 8 distinct 4-bank spans x2 lanes = 2-way = free (m136).
template <int EPI>
__global__ __launch_bounds__(256, 2) void mgemm_k(MP p) {
  __shared__ ushort sAh[128 * 40], sAl[128 * 40], sBh[128 * 40], sBl[128 * 40];
  const int tid = threadIdx.x;
  const int m0 = blockIdx.y * 128, n0 = blockIdx.x * 128;
  const int l = tid & 63, w = tid >> 6;
  const int wm = (w >> 1) * 64, wn = (w & 1) * 64;
  const int fr = l & 15, fq = l >> 4;

  f32x4v acc[4][4];
#pragma unroll
  for (int i = 0; i < 4; ++i)
#pragma unroll
    for (int j = 0; j < 4; ++j)
#pragma unroll
      for (int r = 0; r < 4; ++r) acc[i][j][r] = 0.f;

  const int srow = tid >> 2;   // 0..63
  const int skg  = tid & 3;    // 16B chunk within 64B of k-row

  for (int k0 = 0; k0 < p.K; k0 += 32) {
#pragma unroll
    for (int pass = 0; pass < 2; ++pass) {
      const int row = srow + pass * 64;
      const int lo_off = row * 40 + skg * 8;
      // A pair (M-guarded, zero-fill)
      {
        const int mg = m0 + row;
        uint4 vh = make_uint4(0, 0, 0, 0), vl = make_uint4(0, 0, 0, 0);
        if (mg < p.M) {
          const long long off = (long long)mg * p.lda + k0 + skg * 8;
          vh = *reinterpret_cast<const uint4*>(p.Ah + off);
          vl = *reinterpret_cast<const uint4*>(p.Al + off);
        }
        *reinterpret_cast<uint4*>(&sAh[lo_off]) = vh;
        *reinterpret_cast<uint4*>(&sAl[lo_off]) = vl;
      }
      // W pair (N is always a multiple of 128 here)
      {
        const int ng = n0 + row;
        const long long off = (long long)ng * p.ldw + k0 + skg * 8;
        *reinterpret_cast<uint4*>(&sBh[lo_off]) =
            *reinterpret_cast<const uint4*>(p.Wh + off);
        *reinterpret_cast<uint4*>(&sBl[lo_off]) =
            *reinterpret_cast<const uint4*>(p.Wl + off);
      }
    }
    __syncthreads();

    bf16x8v ah[4], al[4];
#pragma unroll
    for (int mi = 0; mi < 4; ++mi) {
      const int ro = (wm + mi * 16 + fr) * 40 + fq * 8;
      ah[mi] = *reinterpret_cast<const bf16x8v*>(&sAh[ro]);
      al[mi] = *reinterpret_cast<const bf16x8v*>(&sAl[ro]);
    }
#pragma unroll
    for (int ni = 0; ni < 4; ++ni) {
      const int ro = (wn + ni * 16 + fr) * 40 + fq * 8;
      const bf16x8v bh = *reinterpret_cast<const bf16x8v*>(&sBh[ro]);
      const bf16x8v bl = *reinterpret_cast<const bf16x8v*>(&sBl[ro]);
#pragma unroll
      for (int mi = 0; mi < 4; ++mi) {
        acc[mi][ni] = __builtin_amdgcn_mfma_f32_16x16x32_bf16(al[mi], bh, acc[mi][ni], 0, 0, 0);
        acc[mi][ni] = __builtin_amdgcn_mfma_f32_16x16x32_bf16(ah[mi], bl, acc[mi][ni], 0, 0, 0);
        acc[mi][ni] = __builtin_amdgcn_mfma_f32_16x16x32_bf16(ah[mi], bh, acc[mi][ni], 0, 0, 0);
      }
    }
    __syncthreads();
  }

  // epilogue: D[row=(l>>4)*4+reg][col=l&15]  (m89/m91-verified mapping)
#pragma unroll
  for (int mi = 0; mi < 4; ++mi) {
    const int rb = m0 + wm + mi * 16 + fq * 4;
#pragma unroll
    for (int ni = 0; ni < 4; ++ni) {
      const int col = n0 + wn + ni * 16 + fr;
#pragma unroll
      for (int r = 0; r < 4; ++r) {
        const int mg = rb + r;
        if (mg >= p.M) continue;
        float v = acc[mi][ni][r];
        if (EPI == ME_BIAS) {
          p.C[(long long)mg * p.ldc + col] = v + p.bias[col];
        } else if (EPI == ME_RESID_BIAS) {
          p.C[(long long)mg * p.ldc + col] =
              v + p.bias[col] + p.R[(long long)mg * p.ldr + col];
        } else {  // ME_GELU_SPLIT
          v += p.bias[col];
          v = 0.5f * v * (1.f + erff(v * 0.70710678118654752f));
          const ushort h = f2bf(v);
          const long long o = (long long)mg * p.ldo + col;
          p.Oh[o] = h;
          p.Ol[o] = f2bf(v - bf2f(h));
        }
      }
    }
  }
}

template <int EPI>
static void launch_mgemm(hipStream_t st, const MP& p) {
  dim3 grid(p.N / 128, (p.M + 127) / 128);
  hipLaunchKernelGGL(HIP_KERNEL_NAME(mgemm_k<EPI>), grid, dim3(256), 0, st, p);
}

// ====================== f32 VALU GEMM (attention/fusion) ====================
struct GemmP {
  const float* A; long long sA1, sA2; int lda;
  const float* W; long long sW1, sW2; int ldw;
  float*       C; long long sC1, sC2; int ldc;
  const float* R; long long sR1, sR2; int ldr;
  const float* bias;
  const float* scaleptr;
  int M, N, K, Z2;
  float alpha;
};

enum { E_NONE = 0, E_BIAS = 1, E_RESID_SCALE = 4 };

template <int BM, int BN, int BK, int TM, int TN, bool WT, int EPI>
__global__ __launch_bounds__(256) void gemm_k(GemmP p) {
  constexpr int NX = BN / TN;
  __shared__ float As[BK][BM + 4];
  __shared__ float Ws[BK][BN + 4];

  const int tid = threadIdx.x;
  const int z = blockIdx.z;
  const int z1 = z / p.Z2, z2 = z % p.Z2;
  const float* A = p.A + (long long)z1 * p.sA1 + (long long)z2 * p.sA2;
  const float* W = p.W + (long long)z1 * p.sW1 + (long long)z2 * p.sW2;
  float*       C = p.C + (long long)z1 * p.sC1 + (long long)z2 * p.sC2;
  const float* R = p.R ? p.R + (long long)z1 * p.sR1 + (long long)z2 * p.sR2 : nullptr;

  const int m0 = blockIdx.y * BM;
  const int n0 = blockIdx.x * BN;
  const int tx = tid % NX;
  const int ty = tid / NX;

  float acc[TM][TN];
#pragma unroll
  for (int i = 0; i < TM; ++i)
#pragma unroll
    for (int j = 0; j < TN; ++j) acc[i][j] = 0.f;

  for (int k0 = 0; k0 < p.K; k0 += BK) {
    for (int l = tid; l < BM * BK; l += 256) {
      const int m = l / BK, kc = l % BK;
      const int mg = m0 + m, kg = k0 + kc;
      float v = 0.f;
      if (mg < p.M && kg < p.K) v = A[(long long)mg * p.lda + kg];
      As[kc][m] = v;
    }
    if (!WT) {
      for (int l = tid; l < BK * BN; l += 256) {
        const int kc = l / BN, n = l % BN;
        const int ng = n0 + n, kg = k0 + kc;
        float v = 0.f;
        if (ng < p.N && kg < p.K) v = W[(long long)kg * p.ldw + ng];
        Ws[kc][n] = v;
      }
    } else {
      for (int l = tid; l < BK * BN; l += 256) {
        const int n = l / BK, kc = l % BK;
        const int ng = n0 + n, kg = k0 + kc;
        float v = 0.f;
        if (ng < p.N && kg < p.K) v = W[(long long)ng * p.ldw + kg];
        Ws[kc][n] = v;
      }
    }
    __syncthreads();

#pragma unroll
    for (int kk = 0; kk < BK; ++kk) {
      float af[TM], wf[TN];
#pragma unroll
      for (int i = 0; i < TM; i += 4) {
        const float4 t = *reinterpret_cast<const float4*>(&As[kk][ty * TM + i]);
        af[i] = t.x; af[i + 1] = t.y; af[i + 2] = t.z; af[i + 3] = t.w;
      }
#pragma unroll
      for (int j = 0; j < TN; j += 4) {
        const float4 t = *reinterpret_cast<const float4*>(&Ws[kk][tx * TN + j]);
        wf[j] = t.x; wf[j + 1] = t.y; wf[j + 2] = t.z; wf[j + 3] = t.w;
      }
#pragma unroll
      for (int i = 0; i < TM; ++i)
#pragma unroll
        for (int j = 0; j < TN; ++j) acc[i][j] += af[i] * wf[j];
    }
    __syncthreads();
  }

  float sc = 0.f;
  if (EPI == E_RESID_SCALE) sc = p.scaleptr[0];
#pragma unroll
  for (int i = 0; i < TM; ++i) {
    const int mg = m0 + ty * TM + i;
    if (mg >= p.M) continue;
#pragma unroll
    for (int j = 0; j < TN; ++j) {
      const int ng = n0 + tx * TN + j;
      if (ng >= p.N) continue;
      float v = acc[i][j];
      if (EPI == E_NONE) v *= p.alpha;
      if (EPI == E_BIAS) v += p.bias[ng];
      if (EPI == E_RESID_SCALE) v = R[(long long)mg * p.ldr + ng] + sc * v;
      C[(long long)mg * p.ldc + ng] = v;
    }
  }
}

template <int BM, int BN, int BK, int TM, int TN, bool WT, int EPI>
static void launch_gemm(hipStream_t st, const GemmP& p, int Z) {
  dim3 grid((p.N + BN - 1) / BN, (p.M + BM - 1) / BM, Z);
  hipLaunchKernelGGL(HIP_KERNEL_NAME(gemm_k<BM, BN, BK, TM, TN, WT, EPI>),
                     grid, dim3(256), 0, st, p);
}

// ============================ helper kernels ================================

__global__ __launch_bounds__(256) void concat_k(const float* __restrict__ x,
                                                const float* __restrict__ y,
                                                float* __restrict__ c) {
  const long long total4 = (long long)BB * N2 * DD / 4;
  const long long i = (long long)blockIdx.x * 256 + threadIdx.x;
  if (i >= total4) return;
  const long long e = i * 4;
  const int b = (int)(e / ((long long)N2 * DD));
  const long long rem = e % ((long long)N2 * DD);
  const int r = (int)(rem / DD);
  const int col = (int)(rem % DD);
  const float* src = (r < NN) ? (x + ((long long)b * NN + r) * DD + col)
                              : (y + ((long long)b * NN + (r - NN)) * DD + col);
  reinterpret_cast<float4*>(c)[i] = *reinterpret_cast<const float4*>(src);
}

// LayerNorm over D=768 -> hi/lo bf16 pair
__global__ __launch_bounds__(256) void ln_split_k(const float* __restrict__ in,
                                                  ushort* __restrict__ oh,
                                                  ushort* __restrict__ ol,
                                                  const float* __restrict__ g,
                                                  const float* __restrict__ b) {
  const int row = blockIdx.x;
  const int tid = threadIdx.x;
  const float* src = in + (long long)row * DD;
  const float v0 = src[tid], v1 = src[tid + 256], v2 = src[tid + 512];
  __shared__ float red[4];
  const int wid = tid >> 6;

  float s = v0 + v1 + v2;
#pragma unroll
  for (int o = 32; o; o >>= 1) s += __shfl_xor(s, o);
  if ((tid & 63) == 0) red[wid] = s;
  __syncthreads();
  const float mu = (red[0] + red[1] + red[2] + red[3]) * (1.f / 768.f);
  const float d0 = v0 - mu, d1 = v1 - mu, d2 = v2 - mu;
  __syncthreads();

  float q = d0 * d0 + d1 * d1 + d2 * d2;
#pragma unroll
  for (int o = 32; o; o >>= 1) q += __shfl_xor(q, o);
  if ((tid & 63) == 0) red[wid] = q;
  __syncthreads();
  const float var = (red[0] + red[1] + red[2] + red[3]) * (1.f / 768.f);
  const float rs = 1.f / sqrtf(var + 1e-6f);

  ushort* dh = oh + (long long)row * DD;
  ushort* dl = ol + (long long)row * DD;
#pragma unroll
  for (int c = 0; c < 3; ++c) {
    const int idx = tid + c * 256;
    const float dv = (c == 0 ? d0 : c == 1 ? d1 : d2);
    const float v = dv * rs * g[idx] + b[idx];
    const ushort h = f2bf(v);
    dh[idx] = h;
    dl[idx] = f2bf(v - bf2f(h));
  }
}

// f32 [n] -> hi/lo bf16 (vectorized by 4)
__global__ __launch_bounds__(256) void split_k(const float* __restrict__ in,
                                               ushort* __restrict__ oh,
                                               ushort* __restrict__ ol,
                                               long long n4) {
  const long long i = (long long)blockIdx.x * 256 + threadIdx.x;
  if (i >= n4) return;
  const float4 v = reinterpret_cast<const float4*>(in)[i];
  ushort4 h, lo;
  h.x = f2bf(v.x); lo.x = f2bf(v.x - bf2f(h.x));
  h.y = f2bf(v.y); lo.y = f2bf(v.y - bf2f(h.y));
  h.z = f2bf(v.z); lo.z = f2bf(v.z - bf2f(h.z));
  h.w = f2bf(v.w); lo.w = f2bf(v.w - bf2f(h.w));
  reinterpret_cast<ushort4*>(oh)[i] = h;
  reinterpret_cast<ushort4*>(ol)[i] = lo;
}

// W [K][N] f32 -> Wt hi/lo bf16 [N][K]  (32x32 LDS transpose tiles)
__global__ __launch_bounds__(256) void wsplit_k(const float* __restrict__ W,
                                                ushort* __restrict__ th,
                                                ushort* __restrict__ tl,
                                                int K, int N) {
  __shared__ float t[32][33];
  const int tid = threadIdx.x;
  const int kb = blockIdx.y * 32, nb = blockIdx.x * 32;
  for (int u = tid; u < 1024; u += 256) {
    const int k = u >> 5, n = u & 31;
    t[k][n] = W[(long long)(kb + k) * N + nb + n];
  }
  __syncthreads();
  const int n = tid >> 3, k4 = tid & 7;
  ushort4 vh, vl;
  {
    float v;
    v = t[k4 * 4 + 0][n]; vh.x = f2bf(v); vl.x = f2bf(v - bf2f(vh.x));
    v = t[k4 * 4 + 1][n]; vh.y = f2bf(v); vl.y = f2bf(v - bf2f(vh.y));
    v = t[k4 * 4 + 2][n]; vh.z = f2bf(v); vl.z = f2bf(v - bf2f(vh.z));
    v = t[k4 * 4 + 3][n]; vh.w = f2bf(v); vl.w = f2bf(v - bf2f(vh.w));
  }
  const long long o = (long long)(nb + n) * K + kb + k4 * 4;
  *reinterpret_cast<ushort4*>(th + o) = vh;
  *reinterpret_cast<ushort4*>(tl + o) = vl;
}

// ---- softmax kernels ----
__global__ __launch_bounds__(256) void sm1_k(const float* __restrict__ S1t,
                                             float* __restrict__ A2) {
  const int b = blockIdx.x >> 5, l = blockIdx.x & 31;
  const int tid = threadIdx.x;
  const float* src = S1t + (long long)b * N2 * LL + l;
  const bool has2 = (tid + 256) < N2;
  const float v0 = src[(long long)tid * LL];
  const float v1 = has2 ? src[(long long)(tid + 256) * LL] : -3.0e38f;

  __shared__ float red[4];
  const int wid = tid >> 6;
  float mx = fmaxf(v0, v1);
#pragma unroll
  for (int o = 32; o; o >>= 1) mx = fmaxf(mx, __shfl_xor(mx, o));
  if ((tid & 63) == 0) red[wid] = mx;
  __syncthreads();
  mx = fmaxf(fmaxf(red[0], red[1]), fmaxf(red[2], red[3]));
  __syncthreads();

  const float p0 = expf(v0 - mx);
  const float p1 = has2 ? expf(v1 - mx) : 0.f;
  float s = p0 + p1;
#pragma unroll
  for (int o = 32; o; o >>= 1) s += __shfl_xor(s, o);
  if ((tid & 63) == 0) red[wid] = s;
  __syncthreads();
  const float inv = 1.f / (red[0] + red[1] + red[2] + red[3]);

  float* dst = A2 + (long long)b * LL * N2 + (long long)l * N2;
  dst[tid] = p0 * inv;
  if (has2) dst[tid + 256] = p1 * inv;
}

__global__ __launch_bounds__(256) void sm2_k(float* __restrict__ S, int rows) {
  const long long i = (long long)blockIdx.x * 256 + threadIdx.x;
  if (i >= rows) return;
  float* r = S + i * 32;
  float v[32];
  const float4* r4 = reinterpret_cast<const float4*>(r);
#pragma unroll
  for (int j = 0; j < 8; ++j) {
    const float4 t = r4[j];
    v[4 * j] = t.x; v[4 * j + 1] = t.y; v[4 * j + 2] = t.z; v[4 * j + 3] = t.w;
  }
  float mx = v[0];
#pragma unroll
  for (int j = 1; j < 32; ++j) mx = fmaxf(mx, v[j]);
  float s = 0.f;
#pragma unroll
  for (int j = 0; j < 32; ++j) { v[j] = expf(v[j] - mx); s += v[j]; }
  const float inv = 1.f / s;
  float4* w4 = reinterpret_cast<float4*>(r);
#pragma unroll
  for (int j = 0; j < 8; ++j) {
    float4 t;
    t.x = v[4 * j] * inv; t.y = v[4 * j + 1] * inv;
    t.z = v[4 * j + 2] * inv; t.w = v[4 * j + 3] * inv;
    w4[j] = t;
  }
}

__global__ __launch_bounds__(256) void smS_k(float* __restrict__ S, long long rows) {
  const int lane = threadIdx.x & 63;
  const long long row = (long long)blockIdx.x * 4 + (threadIdx.x >> 6);
  if (row >= rows) return;
  float* r = S + row * NN;
  float v[4];
#pragma unroll
  for (int j = 0; j < 4; ++j) {
    const int idx = lane + j * 64;
    v[j] = (idx < NN) ? r[idx] : -3.0e38f;
  }
  float mx = fmaxf(fmaxf(v[0], v[1]), fmaxf(v[2], v[3]));
#pragma unroll
  for (int o = 32; o; o >>= 1) mx = fmaxf(mx, __shfl_xor(mx, o));
  float pv[4];
  float s = 0.f;
#pragma unroll
  for (int j = 0; j < 4; ++j) {
    const int idx = lane + j * 64;
    pv[j] = (idx < NN) ? expf(v[j] - mx) : 0.f;
    s += pv[j];
  }
#pragma unroll
  for (int o = 32; o; o >>= 1) s += __shfl_xor(s, o);
  const float inv = 1.f / s;
#pragma unroll
  for (int j = 0; j < 4; ++j) {
    const int idx = lane + j * 64;
    if (idx < NN) r[idx] = pv[j] * inv;
  }
}

static GemmP mk(const float* A, long long sA1, long long sA2, int lda,
                const float* W, long long sW1, long long sW2, int ldw,
                float* C, long long sC1, long long sC2, int ldc,
                int M, int N, int K, int Z2, float alpha,
                const float* bias = nullptr,
                const float* R = nullptr, long long sR1 = 0, long long sR2 = 0, int ldr = 0,
                const float* scaleptr = nullptr) {
  GemmP p;
  p.A = A; p.sA1 = sA1; p.sA2 = sA2; p.lda = lda;
  p.W = W; p.sW1 = sW1; p.sW2 = sW2; p.ldw = ldw;
  p.C = C; p.sC1 = sC1; p.sC2 = sC2; p.ldc = ldc;
  p.R = R; p.sR1 = sR1; p.sR2 = sR2; p.ldr = ldr;
  p.bias = bias; p.scaleptr = scaleptr;
  p.M = M; p.N = N; p.K = K; p.Z2 = Z2; p.alpha = alpha;
  return p;
}

static MP mkm(const ushort* Ah, const ushort* Al, int lda,
              const ushort* Wh, const ushort* Wl, int ldw,
              int M, int N, int K, const float* bias,
              float* C = nullptr, int ldc = 0,
              const float* R = nullptr, int ldr = 0,
              ushort* Oh = nullptr, ushort* Ol = nullptr, int ldo = 0) {
  MP p;
  p.Ah = Ah; p.Al = Al; p.lda = lda;
  p.Wh = Wh; p.Wl = Wl; p.ldw = ldw;
  p.C = C; p.ldc = ldc; p.bias = bias;
  p.R = R; p.ldr = ldr;
  p.Oh = Oh; p.Ol = Ol; p.ldo = ldo;
  p.M = M; p.N = N; p.K = K;
  return p;
}

}  // namespace

extern "C" void kernel_launch(void* const* d_in, const int* in_sizes, int n_in,
                              void* d_out, int out_size, void* d_ws, size_t ws_size,
                              hipStream_t stream) {
  const float* x   = (const float*)d_in[0];
  const float* y   = (const float*)d_in[1];
  const float* lat = (const float*)d_in[2];
  const float* scale_a = (const float*)d_in[3];
  const float* scale_v = (const float*)d_in[4];
  const float* PRM[2][12];
  for (int i = 0; i < 12; ++i) {
    PRM[0][i] = (const float*)d_in[5 + i];
    PRM[1][i] = (const float*)d_in[17 + i];
  }

  char* ws = (char*)d_ws;
  ushort* Ahi = (ushort*)(ws + B_AHI);
  ushort* Alo = (ushort*)(ws + B_ALO);
  ushort* Ghi = (ushort*)(ws + B_GHI);
  ushort* Glo = (ushort*)(ws + B_GLO);
  float* concat = (float*)(ws + B_CONCAT);
  float* scores = (float*)(ws + B_SCORES);
  float* qkv    = (float*)(ws + B_QKV);
  float* fused  = (float*)(ws + B_FUSED);
  float* S1t    = (float*)(ws + B_S1T);
  float* A2     = (float*)(ws + B_A2);
  float* S2     = (float*)(ws + B_S2);
  float* P1     = (float*)(ws + B_P1);
  ushort* Whi   = (ushort*)(ws + B_WHI);
  ushort* Wlo   = (ushort*)(ws + B_WLO);

  float* outX = (float*)d_out;
  float* outY = outX + (long long)ROWS * DD;

  // ======================= Stage A: fusion attention =======================
  {
    const long long tot4 = (long long)BB * N2 * DD / 4;
    concat_k<<<(unsigned)((tot4 + 255) / 256), 256, 0, stream>>>(x, y, concat);
  }
  launch_gemm<128, 32, 8, 4, 4, true, E_NONE>(
      stream,
      mk(concat, (long long)N2 * DD, 0, DD,
         lat, 0, 0, DD,
         S1t, (long long)N2 * LL, 0, LL,
         N2, LL, DD, 1, SCALE_D),
      BB);
  sm1_k<<<BB * LL, 256, 0, stream>>>(S1t, A2);
  launch_gemm<32, 128, 8, 4, 4, false, E_NONE>(
      stream,
      mk(A2, (long long)LL * N2, 0, N2,
         concat, (long long)N2 * DD, 0, DD,
         fused, (long long)LL * DD, 0, DD,
         LL, DD, N2, 1, 1.f),
      BB);
  for (int s = 0; s < 2; ++s) {
    const float* q = s == 0 ? x : y;
    const float* sp = s == 0 ? scale_a : scale_v;
    float* out = s == 0 ? outX : outY;
    launch_gemm<128, 32, 8, 4, 4, true, E_NONE>(
        stream,
        mk(q, (long long)NN * DD, 0, DD,
           fused, (long long)LL * DD, 0, DD,
           S2, (long long)NN * LL, 0, LL,
           NN, LL, DD, 1, SCALE_D),
        BB);
    sm2_k<<<(BB * NN + 255) / 256, 256, 0, stream>>>(S2, BB * NN);
    launch_gemm<128, 128, 8, 8, 8, false, E_RESID_SCALE>(
        stream,
        mk(S2, (long long)NN * LL, 0, LL,
           fused, (long long)LL * DD, 0, DD,
           out, (long long)NN * DD, 0, DD,
           NN, DD, LL, 1, 1.f,
           nullptr,
           q, (long long)NN * DD, 0, DD,
           sp),
        BB);
  }

  // ==================== Per-stream transformer block ====================
  const long long splitN4 = (long long)ROWS * DD / 4;
  for (int s = 0; s < 2; ++s) {
    float* out = s == 0 ? outX : outY;
    const float* const* pp = PRM[s];
    const float *n1g = pp[0], *n1b = pp[1], *qkvw = pp[2], *qkvb = pp[3],
                *projw = pp[4], *projb = pp[5], *n2g = pp[6], *n2b = pp[7],
                *fc1w = pp[8], *fc1b = pp[9], *fc2w = pp[10], *fc2b = pp[11];

    // h = LN(out) -> hi/lo bf16
    ln_split_k<<<ROWS, 256, 0, stream>>>(out, Ahi, Alo, n1g, n1b);
    // qkv = h @ qkv_w + qkv_b  (MFMA)
    wsplit_k<<<dim3(3 * DD / 32, DD / 32), 256, 0, stream>>>(qkvw, Whi, Wlo, DD, 3 * DD);
    launch_mgemm<ME_BIAS>(stream,
        mkm(Ahi, Alo, DD, Whi, Wlo, DD, ROWS, 3 * DD, DD, qkvb, qkv, 3 * DD));
    // scores = scale * Q @ K^T  (VALU, batched B*H)
    launch_gemm<128, 128, 8, 8, 8, true, E_NONE>(
        stream,
        mk(qkv + 0 * DD, (long long)NN * 3 * DD, HDIM, 3 * DD,
           qkv + 1 * DD, (long long)NN * 3 * DD, HDIM, 3 * DD,
           scores, (long long)HH * NN * NN, (long long)NN * NN, NN,
           NN, NN, HDIM, HH, SCALE_H),
        BB * HH);
    smS_k<<<(unsigned)(((long long)BB * HH * NN + 3) / 4), 256, 0, stream>>>(
        scores, (long long)BB * HH * NN);
    // attn_out = S @ V  (VALU) -> P1
    launch_gemm<128, 64, 8, 8, 4, false, E_NONE>(
        stream,
        mk(scores, (long long)HH * NN * NN, (long long)NN * NN, NN,
           qkv + 2 * DD, (long long)NN * 3 * DD, HDIM, 3 * DD,
           P1, (long long)NN * DD, HDIM, DD,
           NN, HDIM, NN, HH, 1.f),
        BB * HH);
    // out += attn_out @ proj_w + proj_b  (MFMA)
    split_k<<<(unsigned)((splitN4 + 255) / 256), 256, 0, stream>>>(P1, Ahi, Alo, splitN4);
    wsplit_k<<<dim3(DD / 32, DD / 32), 256, 0, stream>>>(projw, Whi, Wlo, DD, DD);
    launch_mgemm<ME_RESID_BIAS>(stream,
        mkm(Ahi, Alo, DD, Whi, Wlo, DD, ROWS, DD, DD, projb, out, DD, out, DD));
    // h2 = LN(out) -> hi/lo
    ln_split_k<<<ROWS, 256, 0, stream>>>(out, Ahi, Alo, n2g, n2b);
    // ff = gelu(h2 @ fc1_w + fc1_b) -> hi/lo bf16  (MFMA)
    wsplit_k<<<dim3(FF / 32, DD / 32), 256, 0, stream>>>(fc1w, Whi, Wlo, DD, FF);
    launch_mgemm<ME_GELU_SPLIT>(stream,
        mkm(Ahi, Alo, DD, Whi, Wlo, DD, ROWS, FF, DD, fc1b,
            nullptr, 0, nullptr, 0, Ghi, Glo, FF));
    // out += ff @ fc2_w + fc2_b  (MFMA)
    wsplit_k<<<dim3(DD / 32, FF / 32), 256, 0, stream>>>(fc2w, Whi, Wlo, FF, DD);
    launch_mgemm<ME_RESID_BIAS>(stream,
        mkm(Ghi, Glo, FF, Whi, Wlo, FF, ROWS, DD, FF, fc2b, out, DD, out, DD));
  }
}

// Round 6
// 3020.222 us; speedup vs baseline: 1.0330x; 1.0330x over previous
//
#include <hip/hip_runtime.h>
#include <math.h>

// ============================================================================
// VanillaEncoder — round 6: R5 staging rewrite + RACE FIX.
// R5 (unbenched) introduced a live overlap: PV E_SPLIT wrote Ahi/Alo which
// alias scores (both at ws offset 0) while PV was still reading scores.
// Fix: PV writes PHI/PLO in the free former-P1 region [258998272, 297730048);
// proj mgemm consumes that pair. All other R5 changes held:
//   1. mgemm: global_load_lds width-16 staging (wave w stages buffer w),
//      linear [128][32] LDS (64B rows), 32KB LDS, __launch_bounds__(256,3).
//   2. mgemm: bijective XCD swizzle (m204) on a 1D grid.
//   3. PV VALU-GEMM writes hi/lo bf16 directly (split_k pass removed).
// R4 baseline (passed, absmax 0.0156): total 3120us, mgemm 272us x6,
// MfmaUtil 27%, FETCH 585MB/dispatch, conflicts 2.9e7.
// ============================================================================

namespace {

constexpr int BB = 64, NN = 197, DD = 768, HH = 12, HDIM = 64, FF = 3072, LL = 32;
constexpr int N2 = 2 * NN;                 // 394
constexpr int ROWS = BB * NN;              // 12608
constexpr float SCALE_D = 0.036084391824351615f;  // 768^-0.5
constexpr float SCALE_H = 0.125f;                 // 64^-0.5

// ---- workspace byte offsets (alias-audited R2-R6) ----
constexpr long long B_AHI    = 0;
constexpr long long B_ALO    = 19365888;
constexpr long long B_GHI    = 40894464;
constexpr long long B_GLO    = 118358016;
constexpr long long B_CONCAT = 0;
constexpr long long B_SCORES = 0;
constexpr long long B_QKV    = 125829120;
constexpr long long B_FUSED  = 242221056;
constexpr long long B_S1T    = 248512512;
constexpr long long B_A2     = 252706816;
constexpr long long B_S2     = 256901120;
constexpr long long B_PHI    = 258998272;   // PV attn_out hi  (former P1)
constexpr long long B_PLO    = 278364160;   // PV attn_out lo
constexpr long long B_WHI    = 297795584;
constexpr long long B_WLO    = 303038464;

__device__ inline ushort f2bf(float f) {
  unsigned x = __float_as_uint(f);
  unsigned r = (x + 0x7FFFu + ((x >> 16) & 1u)) >> 16;
  return (ushort)r;
}
__device__ inline float bf2f(ushort u) {
  return __uint_as_float(((unsigned)u) << 16);
}

// ============================ MFMA bf16x3 GEMM =============================
using bf16x8v = __attribute__((ext_vector_type(8))) short;
using f32x4v  = __attribute__((ext_vector_type(4))) float;

enum { ME_BIAS = 0, ME_RESID_BIAS = 1, ME_GELU_SPLIT = 2 };

struct MP {
  const ushort* Ah; const ushort* Al; int lda;   // A pair, [M][lda] bf16
  const ushort* Wh; const ushort* Wl; int ldw;   // W pair, [N][ldw] bf16 (pre-transposed)
  float* C; int ldc;                              // f32 out (BIAS / RESID_BIAS)
  const float* bias;
  const float* R; int ldr;                        // residual (RESID_BIAS)
  ushort* Oh; ushort* Ol; int ldo;                // bf16 pair out (GELU_SPLIT)
  int M, N, K;
  int nxb, nwg;                                   // grid geometry (1D swizzled)
};

// BM=BN=128, BK=32, 4 waves (2x2), 64x64/wave, 16x16x32 MFMA x3 (hi/lo split).
// Staging: wave w issues 8x global_load_lds(16B) filling its buffer linearly
// (lane l lands at byte l*16 = row l>>2, chunk l&3 of 64B rows). Linear
// [128][32] rows: frag ds_read_b128 spreads 64 lanes across all granules.
template <int EPI>
__global__ __launch_bounds__(256, 3) void mgemm_k(MP p) {
  __shared__ ushort sAh[128 * 32], sAl[128 * 32], sBh[128 * 32], sBl[128 * 32];
  const int tid = threadIdx.x;

  // ---- bijective XCD swizzle (m204): XCD k owns a contiguous wg-id chunk ----
  const int nwg = p.nwg;
  const int h = blockIdx.x;
  const int q = nwg >> 3, r = nwg & 7;
  const int xcd = h & 7, ii = h >> 3;
  const int wg = (xcd < r ? xcd * (q + 1) : r * (q + 1) + (xcd - r) * q) + ii;
  const int m0 = (wg / p.nxb) * 128;
  const int n0 = (wg % p.nxb) * 128;

  const int l = tid & 63, w = tid >> 6;
  const int wm = (w >> 1) * 64, wn = (w & 1) * 64;
  const int fr = l & 15, fq = l >> 4;

  // staging role: wave w -> buffer w
  ushort* const lbuf = (w == 0) ? sAh : (w == 1) ? sAl : (w == 2) ? sBh : sBl;
  const ushort* const gsrc = (w == 0) ? p.Ah : (w == 1) ? p.Al
                            : (w == 2) ? p.Wh : p.Wl;
  const int ldg   = (w < 2) ? p.lda : p.ldw;
  const int rbase = (w < 2) ? m0 : n0;
  const int rlim  = ((w < 2) ? p.M : p.N) - 1;
  const int rl = l >> 2;   // row within 16-row group
  const int ch = l & 3;    // 16B chunk within 64B row

  f32x4v acc[4][4];
#pragma unroll
  for (int i = 0; i < 4; ++i)
#pragma unroll
    for (int j = 0; j < 4; ++j)
#pragma unroll
      for (int t = 0; t < 4; ++t) acc[i][j][t] = 0.f;

  for (int k0 = 0; k0 < p.K; k0 += 32) {
#pragma unroll
    for (int j = 0; j < 8; ++j) {
      int rg = rbase + j * 16 + rl;
      rg = rg > rlim ? rlim : rg;  // clamp: only feeds discarded output rows
      const ushort* gp = gsrc + (long long)rg * ldg + k0 + ch * 8;
      __builtin_amdgcn_global_load_lds(
          (const __attribute__((address_space(1))) void*)gp,
          (__attribute__((address_space(3))) void*)(lbuf + j * 512),
          16, 0, 0);
    }
    __syncthreads();  // compiler drains vmcnt(0) before barrier

    bf16x8v ah[4], al[4];
#pragma unroll
    for (int mi = 0; mi < 4; ++mi) {
      const int ro = (wm + mi * 16 + fr) * 32 + fq * 8;
      ah[mi] = *reinterpret_cast<const bf16x8v*>(&sAh[ro]);
      al[mi] = *reinterpret_cast<const bf16x8v*>(&sAl[ro]);
    }
#pragma unroll
    for (int ni = 0; ni < 4; ++ni) {
      const int ro = (wn + ni * 16 + fr) * 32 + fq * 8;
      const bf16x8v bh = *reinterpret_cast<const bf16x8v*>(&sBh[ro]);
      const bf16x8v bl = *reinterpret_cast<const bf16x8v*>(&sBl[ro]);
#pragma unroll
      for (int mi = 0; mi < 4; ++mi) {
        acc[mi][ni] = __builtin_amdgcn_mfma_f32_16x16x32_bf16(al[mi], bh, acc[mi][ni], 0, 0, 0);
        acc[mi][ni] = __builtin_amdgcn_mfma_f32_16x16x32_bf16(ah[mi], bl, acc[mi][ni], 0, 0, 0);
        acc[mi][ni] = __builtin_amdgcn_mfma_f32_16x16x32_bf16(ah[mi], bh, acc[mi][ni], 0, 0, 0);
      }
    }
    __syncthreads();
  }

  // epilogue: D[row=(l>>4)*4+reg][col=l&15]  (verified R4: passed)
#pragma unroll
  for (int mi = 0; mi < 4; ++mi) {
    const int rb = m0 + wm + mi * 16 + fq * 4;
#pragma unroll
    for (int ni = 0; ni < 4; ++ni) {
      const int col = n0 + wn + ni * 16 + fr;
#pragma unroll
      for (int t = 0; t < 4; ++t) {
        const int mg = rb + t;
        if (mg >= p.M) continue;
        float v = acc[mi][ni][t];
        if (EPI == ME_BIAS) {
          p.C[(long long)mg * p.ldc + col] = v + p.bias[col];
        } else if (EPI == ME_RESID_BIAS) {
          p.C[(long long)mg * p.ldc + col] =
              v + p.bias[col] + p.R[(long long)mg * p.ldr + col];
        } else {  // ME_GELU_SPLIT
          v += p.bias[col];
          v = 0.5f * v * (1.f + erff(v * 0.70710678118654752f));
          const ushort hh = f2bf(v);
          const long long o = (long long)mg * p.ldo + col;
          p.Oh[o] = hh;
          p.Ol[o] = f2bf(v - bf2f(hh));
        }
      }
    }
  }
}

template <int EPI>
static void launch_mgemm(hipStream_t st, MP p) {
  p.nxb = p.N / 128;
  p.nwg = p.nxb * ((p.M + 127) / 128);
  hipLaunchKernelGGL(HIP_KERNEL_NAME(mgemm_k<EPI>), dim3(p.nwg), dim3(256), 0, st, p);
}

// ====================== f32 VALU GEMM (attention/fusion) ====================
struct GemmP {
  const float* A; long long sA1, sA2; int lda;
  const float* W; long long sW1, sW2; int ldw;
  float*       C; long long sC1, sC2; int ldc;
  const float* R; long long sR1, sR2; int ldr;
  const float* bias;
  const float* scaleptr;
  ushort* Oh; ushort* Ol;                        // E_SPLIT outputs (use sC/ldc)
  int M, N, K, Z2;
  float alpha;
};

enum { E_NONE = 0, E_BIAS = 1, E_RESID_SCALE = 4, E_SPLIT = 5 };

template <int BM, int BN, int BK, int TM, int TN, bool WT, int EPI>
__global__ __launch_bounds__(256) void gemm_k(GemmP p) {
  constexpr int NX = BN / TN;
  __shared__ float As[BK][BM + 4];
  __shared__ float Ws[BK][BN + 4];

  const int tid = threadIdx.x;
  const int z = blockIdx.z;
  const int z1 = z / p.Z2, z2 = z % p.Z2;
  const float* A = p.A + (long long)z1 * p.sA1 + (long long)z2 * p.sA2;
  const float* W = p.W + (long long)z1 * p.sW1 + (long long)z2 * p.sW2;
  float*       C = p.C ? p.C + (long long)z1 * p.sC1 + (long long)z2 * p.sC2 : nullptr;
  const float* R = p.R ? p.R + (long long)z1 * p.sR1 + (long long)z2 * p.sR2 : nullptr;
  ushort* Oh = p.Oh ? p.Oh + (long long)z1 * p.sC1 + (long long)z2 * p.sC2 : nullptr;
  ushort* Ol = p.Ol ? p.Ol + (long long)z1 * p.sC1 + (long long)z2 * p.sC2 : nullptr;

  const int m0 = blockIdx.y * BM;
  const int n0 = blockIdx.x * BN;
  const int tx = tid % NX;
  const int ty = tid / NX;

  float acc[TM][TN];
#pragma unroll
  for (int i = 0; i < TM; ++i)
#pragma unroll
    for (int j = 0; j < TN; ++j) acc[i][j] = 0.f;

  for (int k0 = 0; k0 < p.K; k0 += BK) {
    for (int l = tid; l < BM * BK; l += 256) {
      const int m = l / BK, kc = l % BK;
      const int mg = m0 + m, kg = k0 + kc;
      float v = 0.f;
      if (mg < p.M && kg < p.K) v = A[(long long)mg * p.lda + kg];
      As[kc][m] = v;
    }
    if (!WT) {
      for (int l = tid; l < BK * BN; l += 256) {
        const int kc = l / BN, n = l % BN;
        const int ng = n0 + n, kg = k0 + kc;
        float v = 0.f;
        if (ng < p.N && kg < p.K) v = W[(long long)kg * p.ldw + ng];
        Ws[kc][n] = v;
      }
    } else {
      for (int l = tid; l < BK * BN; l += 256) {
        const int n = l / BK, kc = l % BK;
        const int ng = n0 + n, kg = k0 + kc;
        float v = 0.f;
        if (ng < p.N && kg < p.K) v = W[(long long)ng * p.ldw + kg];
        Ws[kc][n] = v;
      }
    }
    __syncthreads();

#pragma unroll
    for (int kk = 0; kk < BK; ++kk) {
      float af[TM], wf[TN];
#pragma unroll
      for (int i = 0; i < TM; i += 4) {
        const float4 t = *reinterpret_cast<const float4*>(&As[kk][ty * TM + i]);
        af[i] = t.x; af[i + 1] = t.y; af[i + 2] = t.z; af[i + 3] = t.w;
      }
#pragma unroll
      for (int j = 0; j < TN; j += 4) {
        const float4 t = *reinterpret_cast<const float4*>(&Ws[kk][tx * TN + j]);
        wf[j] = t.x; wf[j + 1] = t.y; wf[j + 2] = t.z; wf[j + 3] = t.w;
      }
#pragma unroll
      for (int i = 0; i < TM; ++i)
#pragma unroll
        for (int j = 0; j < TN; ++j) acc[i][j] += af[i] * wf[j];
    }
    __syncthreads();
  }

  float sc = 0.f;
  if (EPI == E_RESID_SCALE) sc = p.scaleptr[0];
#pragma unroll
  for (int i = 0; i < TM; ++i) {
    const int mg = m0 + ty * TM + i;
    if (mg >= p.M) continue;
#pragma unroll
    for (int j = 0; j < TN; ++j) {
      const int ng = n0 + tx * TN + j;
      if (ng >= p.N) continue;
      float v = acc[i][j];
      if (EPI == E_NONE) v *= p.alpha;
      if (EPI == E_BIAS) v += p.bias[ng];
      if (EPI == E_RESID_SCALE) v = R[(long long)mg * p.ldr + ng] + sc * v;
      if (EPI == E_SPLIT) {
        const long long o = (long long)mg * p.ldc + ng;
        const ushort hh = f2bf(v);
        Oh[o] = hh;
        Ol[o] = f2bf(v - bf2f(hh));
      } else {
        C[(long long)mg * p.ldc + ng] = v;
      }
    }
  }
}

template <int BM, int BN, int BK, int TM, int TN, bool WT, int EPI>
static void launch_gemm(hipStream_t st, const GemmP& p, int Z) {
  dim3 grid((p.N + BN - 1) / BN, (p.M + BM - 1) / BM, Z);
  hipLaunchKernelGGL(HIP_KERNEL_NAME(gemm_k<BM, BN, BK, TM, TN, WT, EPI>),
                     grid, dim3(256), 0, st, p);
}

// ============================ helper kernels ================================

__global__ __launch_bounds__(256) void concat_k(const float* __restrict__ x,
                                                const float* __restrict__ y,
                                                float* __restrict__ c) {
  const long long total4 = (long long)BB * N2 * DD / 4;
  const long long i = (long long)blockIdx.x * 256 + threadIdx.x;
  if (i >= total4) return;
  const long long e = i * 4;
  const int b = (int)(e / ((long long)N2 * DD));
  const long long rem = e % ((long long)N2 * DD);
  const int r = (int)(rem / DD);
  const int col = (int)(rem % DD);
  const float* src = (r < NN) ? (x + ((long long)b * NN + r) * DD + col)
                              : (y + ((long long)b * NN + (r - NN)) * DD + col);
  reinterpret_cast<float4*>(c)[i] = *reinterpret_cast<const float4*>(src);
}

// LayerNorm over D=768 -> hi/lo bf16 pair
__global__ __launch_bounds__(256) void ln_split_k(const float* __restrict__ in,
                                                  ushort* __restrict__ oh,
                                                  ushort* __restrict__ ol,
                                                  const float* __restrict__ g,
                                                  const float* __restrict__ b) {
  const int row = blockIdx.x;
  const int tid = threadIdx.x;
  const float* src = in + (long long)row * DD;
  const float v0 = src[tid], v1 = src[tid + 256], v2 = src[tid + 512];
  __shared__ float red[4];
  const int wid = tid >> 6;

  float s = v0 + v1 + v2;
#pragma unroll
  for (int o = 32; o; o >>= 1) s += __shfl_xor(s, o);
  if ((tid & 63) == 0) red[wid] = s;
  __syncthreads();
  const float mu = (red[0] + red[1] + red[2] + red[3]) * (1.f / 768.f);
  const float d0 = v0 - mu, d1 = v1 - mu, d2 = v2 - mu;
  __syncthreads();

  float qv = d0 * d0 + d1 * d1 + d2 * d2;
#pragma unroll
  for (int o = 32; o; o >>= 1) qv += __shfl_xor(qv, o);
  if ((tid & 63) == 0) red[wid] = qv;
  __syncthreads();
  const float var = (red[0] + red[1] + red[2] + red[3]) * (1.f / 768.f);
  const float rs = 1.f / sqrtf(var + 1e-6f);

  ushort* dh = oh + (long long)row * DD;
  ushort* dl = ol + (long long)row * DD;
#pragma unroll
  for (int c = 0; c < 3; ++c) {
    const int idx = tid + c * 256;
    const float dv = (c == 0 ? d0 : c == 1 ? d1 : d2);
    const float v = dv * rs * g[idx] + b[idx];
    const ushort hh = f2bf(v);
    dh[idx] = hh;
    dl[idx] = f2bf(v - bf2f(hh));
  }
}

// W [K][N] f32 -> Wt hi/lo bf16 [N][K]  (32x32 LDS transpose tiles)
__global__ __launch_bounds__(256) void wsplit_k(const float* __restrict__ W,
                                                ushort* __restrict__ th,
                                                ushort* __restrict__ tl,
                                                int K, int N) {
  __shared__ float t[32][33];
  const int tid = threadIdx.x;
  const int kb = blockIdx.y * 32, nb = blockIdx.x * 32;
  for (int u = tid; u < 1024; u += 256) {
    const int k = u >> 5, n = u & 31;
    t[k][n] = W[(long long)(kb + k) * N + nb + n];
  }
  __syncthreads();
  const int n = tid >> 3, k4 = tid & 7;
  ushort4 vh, vl;
  {
    float v;
    v = t[k4 * 4 + 0][n]; vh.x = f2bf(v); vl.x = f2bf(v - bf2f(vh.x));
    v = t[k4 * 4 + 1][n]; vh.y = f2bf(v); vl.y = f2bf(v - bf2f(vh.y));
    v = t[k4 * 4 + 2][n]; vh.z = f2bf(v); vl.z = f2bf(v - bf2f(vh.z));
    v = t[k4 * 4 + 3][n]; vh.w = f2bf(v); vl.w = f2bf(v - bf2f(vh.w));
  }
  const long long o = (long long)(nb + n) * K + kb + k4 * 4;
  *reinterpret_cast<ushort4*>(th + o) = vh;
  *reinterpret_cast<ushort4*>(tl + o) = vl;
}

// ---- softmax kernels ----
__global__ __launch_bounds__(256) void sm1_k(const float* __restrict__ S1t,
                                             float* __restrict__ A2) {
  const int b = blockIdx.x >> 5, l = blockIdx.x & 31;
  const int tid = threadIdx.x;
  const float* src = S1t + (long long)b * N2 * LL + l;
  const bool has2 = (tid + 256) < N2;
  const float v0 = src[(long long)tid * LL];
  const float v1 = has2 ? src[(long long)(tid + 256) * LL] : -3.0e38f;

  __shared__ float red[4];
  const int wid = tid >> 6;
  float mx = fmaxf(v0, v1);
#pragma unroll
  for (int o = 32; o; o >>= 1) mx = fmaxf(mx, __shfl_xor(mx, o));
  if ((tid & 63) == 0) red[wid] = mx;
  __syncthreads();
  mx = fmaxf(fmaxf(red[0], red[1]), fmaxf(red[2], red[3]));
  __syncthreads();

  const float p0 = expf(v0 - mx);
  const float p1 = has2 ? expf(v1 - mx) : 0.f;
  float s = p0 + p1;
#pragma unroll
  for (int o = 32; o; o >>= 1) s += __shfl_xor(s, o);
  if ((tid & 63) == 0) red[wid] = s;
  __syncthreads();
  const float inv = 1.f / (red[0] + red[1] + red[2] + red[3]);

  float* dst = A2 + (long long)b * LL * N2 + (long long)l * N2;
  dst[tid] = p0 * inv;
  if (has2) dst[tid + 256] = p1 * inv;
}

__global__ __launch_bounds__(256) void sm2_k(float* __restrict__ S, int rows) {
  const long long i = (long long)blockIdx.x * 256 + threadIdx.x;
  if (i >= rows) return;
  float* r = S + i * 32;
  float v[32];
  const float4* r4 = reinterpret_cast<const float4*>(r);
#pragma unroll
  for (int j = 0; j < 8; ++j) {
    const float4 t = r4[j];
    v[4 * j] = t.x; v[4 * j + 1] = t.y; v[4 * j + 2] = t.z; v[4 * j + 3] = t.w;
  }
  float mx = v[0];
#pragma unroll
  for (int j = 1; j < 32; ++j) mx = fmaxf(mx, v[j]);
  float s = 0.f;
#pragma unroll
  for (int j = 0; j < 32; ++j) { v[j] = expf(v[j] - mx); s += v[j]; }
  const float inv = 1.f / s;
  float4* w4 = reinterpret_cast<float4*>(r);
#pragma unroll
  for (int j = 0; j < 8; ++j) {
    float4 t;
    t.x = v[4 * j] * inv; t.y = v[4 * j + 1] * inv;
    t.z = v[4 * j + 2] * inv; t.w = v[4 * j + 3] * inv;
    w4[j] = t;
  }
}

__global__ __launch_bounds__(256) void smS_k(float* __restrict__ S, long long rows) {
  const int lane = threadIdx.x & 63;
  const long long row = (long long)blockIdx.x * 4 + (threadIdx.x >> 6);
  if (row >= rows) return;
  float* r = S + row * NN;
  float v[4];
#pragma unroll
  for (int j = 0; j < 4; ++j) {
    const int idx = lane + j * 64;
    v[j] = (idx < NN) ? r[idx] : -3.0e38f;
  }
  float mx = fmaxf(fmaxf(v[0], v[1]), fmaxf(v[2], v[3]));
#pragma unroll
  for (int o = 32; o; o >>= 1) mx = fmaxf(mx, __shfl_xor(mx, o));
  float pv[4];
  float s = 0.f;
#pragma unroll
  for (int j = 0; j < 4; ++j) {
    const int idx = lane + j * 64;
    pv[j] = (idx < NN) ? expf(v[j] - mx) : 0.f;
    s += pv[j];
  }
#pragma unroll
  for (int o = 32; o; o >>= 1) s += __shfl_xor(s, o);
  const float inv = 1.f / s;
#pragma unroll
  for (int j = 0; j < 4; ++j) {
    const int idx = lane + j * 64;
    if (idx < NN) r[idx] = pv[j] * inv;
  }
}

static GemmP mk(const float* A, long long sA1, long long sA2, int lda,
                const float* W, long long sW1, long long sW2, int ldw,
                float* C, long long sC1, long long sC2, int ldc,
                int M, int N, int K, int Z2, float alpha,
                const float* bias = nullptr,
                const float* R = nullptr, long long sR1 = 0, long long sR2 = 0, int ldr = 0,
                const float* scaleptr = nullptr) {
  GemmP p;
  p.A = A; p.sA1 = sA1; p.sA2 = sA2; p.lda = lda;
  p.W = W; p.sW1 = sW1; p.sW2 = sW2; p.ldw = ldw;
  p.C = C; p.sC1 = sC1; p.sC2 = sC2; p.ldc = ldc;
  p.R = R; p.sR1 = sR1; p.sR2 = sR2; p.ldr = ldr;
  p.bias = bias; p.scaleptr = scaleptr;
  p.Oh = nullptr; p.Ol = nullptr;
  p.M = M; p.N = N; p.K = K; p.Z2 = Z2; p.alpha = alpha;
  return p;
}

static MP mkm(const ushort* Ah, const ushort* Al, int lda,
              const ushort* Wh, const ushort* Wl, int ldw,
              int M, int N, int K, const float* bias,
              float* C = nullptr, int ldc = 0,
              const float* R = nullptr, int ldr = 0,
              ushort* Oh = nullptr, ushort* Ol = nullptr, int ldo = 0) {
  MP p;
  p.Ah = Ah; p.Al = Al; p.lda = lda;
  p.Wh = Wh; p.Wl = Wl; p.ldw = ldw;
  p.C = C; p.ldc = ldc; p.bias = bias;
  p.R = R; p.ldr = ldr;
  p.Oh = Oh; p.Ol = Ol; p.ldo = ldo;
  p.M = M; p.N = N; p.K = K;
  p.nxb = 0; p.nwg = 0;
  return p;
}

}  // namespace

extern "C" void kernel_launch(void* const* d_in, const int* in_sizes, int n_in,
                              void* d_out, int out_size, void* d_ws, size_t ws_size,
                              hipStream_t stream) {
  const float* x   = (const float*)d_in[0];
  const float* y   = (const float*)d_in[1];
  const float* lat = (const float*)d_in[2];
  const float* scale_a = (const float*)d_in[3];
  const float* scale_v = (const float*)d_in[4];
  const float* PRM[2][12];
  for (int i = 0; i < 12; ++i) {
    PRM[0][i] = (const float*)d_in[5 + i];
    PRM[1][i] = (const float*)d_in[17 + i];
  }

  char* ws = (char*)d_ws;
  ushort* Ahi = (ushort*)(ws + B_AHI);
  ushort* Alo = (ushort*)(ws + B_ALO);
  ushort* Ghi = (ushort*)(ws + B_GHI);
  ushort* Glo = (ushort*)(ws + B_GLO);
  float* concat = (float*)(ws + B_CONCAT);
  float* scores = (float*)(ws + B_SCORES);
  float* qkv    = (float*)(ws + B_QKV);
  float* fused  = (float*)(ws + B_FUSED);
  float* S1t    = (float*)(ws + B_S1T);
  float* A2     = (float*)(ws + B_A2);
  float* S2     = (float*)(ws + B_S2);
  ushort* Phi   = (ushort*)(ws + B_PHI);
  ushort* Plo   = (ushort*)(ws + B_PLO);
  ushort* Whi   = (ushort*)(ws + B_WHI);
  ushort* Wlo   = (ushort*)(ws + B_WLO);

  float* outX = (float*)d_out;
  float* outY = outX + (long long)ROWS * DD;

  // ======================= Stage A: fusion attention =======================
  {
    const long long tot4 = (long long)BB * N2 * DD / 4;
    concat_k<<<(unsigned)((tot4 + 255) / 256), 256, 0, stream>>>(x, y, concat);
  }
  launch_gemm<128, 32, 8, 4, 4, true, E_NONE>(
      stream,
      mk(concat, (long long)N2 * DD, 0, DD,
         lat, 0, 0, DD,
         S1t, (long long)N2 * LL, 0, LL,
         N2, LL, DD, 1, SCALE_D),
      BB);
  sm1_k<<<BB * LL, 256, 0, stream>>>(S1t, A2);
  launch_gemm<32, 128, 8, 4, 4, false, E_NONE>(
      stream,
      mk(A2, (long long)LL * N2, 0, N2,
         concat, (long long)N2 * DD, 0, DD,
         fused, (long long)LL * DD, 0, DD,
         LL, DD, N2, 1, 1.f),
      BB);
  for (int s = 0; s < 2; ++s) {
    const float* qq = s == 0 ? x : y;
    const float* sp = s == 0 ? scale_a : scale_v;
    float* out = s == 0 ? outX : outY;
    launch_gemm<128, 32, 8, 4, 4, true, E_NONE>(
        stream,
        mk(qq, (long long)NN * DD, 0, DD,
           fused, (long long)LL * DD, 0, DD,
           S2, (long long)NN * LL, 0, LL,
           NN, LL, DD, 1, SCALE_D),
        BB);
    sm2_k<<<(BB * NN + 255) / 256, 256, 0, stream>>>(S2, BB * NN);
    launch_gemm<128, 128, 8, 8, 8, false, E_RESID_SCALE>(
        stream,
        mk(S2, (long long)NN * LL, 0, LL,
           fused, (long long)LL * DD, 0, DD,
           out, (long long)NN * DD, 0, DD,
           NN, DD, LL, 1, 1.f,
           nullptr,
           qq, (long long)NN * DD, 0, DD,
           sp),
        BB);
  }

  // ==================== Per-stream transformer block ====================
  for (int s = 0; s < 2; ++s) {
    float* out = s == 0 ? outX : outY;
    const float* const* pp = PRM[s];
    const float *n1g = pp[0], *n1b = pp[1], *qkvw = pp[2], *qkvb = pp[3],
                *projw = pp[4], *projb = pp[5], *n2g = pp[6], *n2b = pp[7],
                *fc1w = pp[8], *fc1b = pp[9], *fc2w = pp[10], *fc2b = pp[11];

    // h = LN(out) -> hi/lo bf16
    ln_split_k<<<ROWS, 256, 0, stream>>>(out, Ahi, Alo, n1g, n1b);
    // qkv = h @ qkv_w + qkv_b  (MFMA)
    wsplit_k<<<dim3(3 * DD / 32, DD / 32), 256, 0, stream>>>(qkvw, Whi, Wlo, DD, 3 * DD);
    launch_mgemm<ME_BIAS>(stream,
        mkm(Ahi, Alo, DD, Whi, Wlo, DD, ROWS, 3 * DD, DD, qkvb, qkv, 3 * DD));
    // scores = scale * Q @ K^T  (VALU, batched B*H)
    launch_gemm<128, 128, 8, 8, 8, true, E_NONE>(
        stream,
        mk(qkv + 0 * DD, (long long)NN * 3 * DD, HDIM, 3 * DD,
           qkv + 1 * DD, (long long)NN * 3 * DD, HDIM, 3 * DD,
           scores, (long long)HH * NN * NN, (long long)NN * NN, NN,
           NN, NN, HDIM, HH, SCALE_H),
        BB * HH);
    smS_k<<<(unsigned)(((long long)BB * HH * NN + 3) / 4), 256, 0, stream>>>(
        scores, (long long)BB * HH * NN);
    // attn_out = S @ V  (VALU) -> hi/lo pair into Phi/Plo (no alias w/ scores)
    {
      GemmP pv = mk(scores, (long long)HH * NN * NN, (long long)NN * NN, NN,
                    qkv + 2 * DD, (long long)NN * 3 * DD, HDIM, 3 * DD,
                    nullptr, (long long)NN * DD, HDIM, DD,
                    NN, HDIM, NN, HH, 1.f);
      pv.Oh = Phi; pv.Ol = Plo;
      launch_gemm<128, 64, 8, 8, 4, false, E_SPLIT>(stream, pv, BB * HH);
    }
    // out += attn_out @ proj_w + proj_b  (MFMA, A = Phi/Plo)
    wsplit_k<<<dim3(DD / 32, DD / 32), 256, 0, stream>>>(projw, Whi, Wlo, DD, DD);
    launch_mgemm<ME_RESID_BIAS>(stream,
        mkm(Phi, Plo, DD, Whi, Wlo, DD, ROWS, DD, DD, projb, out, DD, out, DD));
    // h2 = LN(out) -> hi/lo
    ln_split_k<<<ROWS, 256, 0, stream>>>(out, Ahi, Alo, n2g, n2b);
    // ff = gelu(h2 @ fc1_w + fc1_b) -> hi/lo bf16  (MFMA)
    wsplit_k<<<dim3(FF / 32, DD / 32), 256, 0, stream>>>(fc1w, Whi, Wlo, DD, FF);
    launch_mgemm<ME_GELU_SPLIT>(stream,
        mkm(Ahi, Alo, DD, Whi, Wlo, DD, ROWS, FF, DD, fc1b,
            nullptr, 0, nullptr, 0, Ghi, Glo, FF));
    // out += ff @ fc2_w + fc2_b  (MFMA)
    wsplit_k<<<dim3(DD / 32, FF / 32), 256, 0, stream>>>(fc2w, Whi, Wlo, FF, DD);
    launch_mgemm<ME_RESID_BIAS>(stream,
        mkm(Ghi, Glo, FF, Whi, Wlo, FF, ROWS, DD, FF, fc2b, out, DD, out, DD));
  }
}